// Round 2
// baseline (1149.007 us; speedup 1.0000x reference)
//
#include <hip/hip_runtime.h>
#include <stdint.h>
#include <stddef.h>

typedef _Float16 f16;
typedef _Float16 half8 __attribute__((ext_vector_type(8)));
typedef float f32x4 __attribute__((ext_vector_type(4)));

constexpr int kB = 4, kSQ = 512, kSK = 1024, kH = 1024, kHeads = 16, kE = 8, kDFF = 4096;
constexpr int kTok = kB * kSQ;  // 2048 gen tokens

// async global->LDS, 16B per lane; LDS dest must be wave-uniform base + lane*16
__device__ __forceinline__ void g2l16(const f16* g, f16* l) {
  __builtin_amdgcn_global_load_lds((const __attribute__((address_space(1))) uint32_t*)g,
                                   (__attribute__((address_space(3))) uint32_t*)l, 16, 0, 0);
}

// ---------------- transpose + fp32->fp16: dst[C][R] = (f16)src[R][C], batched over z
__global__ __launch_bounds__(256) void tr_f2h(const float* __restrict__ src,
                                              f16* __restrict__ dst, int R, int C) {
  __shared__ float t[32][33];
  long zo = (long)blockIdx.z * R * C;
  int r0 = blockIdx.y * 32, c0 = blockIdx.x * 32;
  int tr = threadIdx.x >> 3, tc = (threadIdx.x & 7) << 2;
  float4 v = *(const float4*)(src + zo + (long)(r0 + tr) * C + c0 + tc);
  t[tr][tc] = v.x; t[tr][tc + 1] = v.y; t[tr][tc + 2] = v.z; t[tr][tc + 3] = v.w;
  __syncthreads();
  union { f16 h[4]; uint2 u; } o;
  o.h[0] = (f16)t[tc + 0][tr]; o.h[1] = (f16)t[tc + 1][tr];
  o.h[2] = (f16)t[tc + 2][tr]; o.h[3] = (f16)t[tc + 3][tr];
  *(uint2*)(dst + zo + (long)(c0 + tr) * R + r0 + tc) = o.u;
}

// ---------------- LayerNorm over H=1024, one block (256 thr) per row --------
__global__ __launch_bounds__(256) void ln_kernel(const float* __restrict__ x,
                                                 const float* __restrict__ g,
                                                 const float* __restrict__ b,
                                                 f16* __restrict__ oh, float* __restrict__ of,
                                                 int rows) {
  int row = blockIdx.x;
  if (row >= rows) return;
  int tid = threadIdx.x;
  const float* xr = x + (long)row * kH;
  float4 v = *(const float4*)(xr + tid * 4);
  float s = v.x + v.y + v.z + v.w;
  float s2 = v.x * v.x + v.y * v.y + v.z * v.z + v.w * v.w;
  __shared__ float red[8];
  for (int o = 32; o; o >>= 1) { s += __shfl_down(s, o); s2 += __shfl_down(s2, o); }
  int wv = tid >> 6, lane = tid & 63;
  if (lane == 0) { red[wv] = s; red[4 + wv] = s2; }
  __syncthreads();
  if (tid == 0) {
    red[0] = red[0] + red[1] + red[2] + red[3];
    red[4] = red[4] + red[5] + red[6] + red[7];
  }
  __syncthreads();
  float mean = red[0] * (1.0f / kH);
  float var = red[4] * (1.0f / kH) - mean * mean;
  float rs = rsqrtf(var + 1e-6f);
  float4 gv = *(const float4*)(g + tid * 4);
  float4 bv = *(const float4*)(b + tid * 4);
  float y0 = (v.x - mean) * rs * gv.x + bv.x;
  float y1 = (v.y - mean) * rs * gv.y + bv.y;
  float y2 = (v.z - mean) * rs * gv.z + bv.z;
  float y3 = (v.w - mean) * rs * gv.w + bv.w;
  long base = (long)row * kH + tid * 4;
  if (oh) {
    union { f16 h[4]; uint2 u; } o;
    o.h[0] = (f16)y0; o.h[1] = (f16)y1; o.h[2] = (f16)y2; o.h[3] = (f16)y3;
    *(uint2*)(oh + base) = o.u;
  }
  if (of) { float4 o4 = {y0, y1, y2, y3}; *(float4*)(of + base) = o4; }
}

// ---------------- row softmax over SK=1024, in place, fp16 ----------------
__global__ __launch_bounds__(256) void softmax_kernel(f16* __restrict__ sc) {
  long row = blockIdx.x;
  f16* p = sc + row * kSK;
  int tid = threadIdx.x;
  union { f16 h[4]; uint2 u; } lv;
  lv.u = *(uint2*)(p + tid * 4);
  float v0 = (float)lv.h[0], v1 = (float)lv.h[1], v2 = (float)lv.h[2], v3 = (float)lv.h[3];
  __shared__ float red[8];
  float mx = fmaxf(fmaxf(v0, v1), fmaxf(v2, v3));
  for (int o = 32; o; o >>= 1) mx = fmaxf(mx, __shfl_down(mx, o));
  int wv = tid >> 6, lane = tid & 63;
  if (lane == 0) red[wv] = mx;
  __syncthreads();
  if (tid == 0) red[0] = fmaxf(fmaxf(red[0], red[1]), fmaxf(red[2], red[3]));
  __syncthreads();
  mx = red[0];
  float e0 = __expf(v0 - mx), e1 = __expf(v1 - mx), e2 = __expf(v2 - mx), e3 = __expf(v3 - mx);
  float s = e0 + e1 + e2 + e3;
  for (int o = 32; o; o >>= 1) s += __shfl_down(s, o);
  if (lane == 0) red[4 + wv] = s;
  __syncthreads();
  if (tid == 0) red[4] = red[4] + red[5] + red[6] + red[7];
  __syncthreads();
  float inv = 1.0f / red[4];
  lv.h[0] = (f16)(e0 * inv); lv.h[1] = (f16)(e1 * inv);
  lv.h[2] = (f16)(e2 * inv); lv.h[3] = (f16)(e3 * inv);
  *(uint2*)(p + tid * 4) = lv.u;
}

__global__ void zero_kernel(int* __restrict__ p, int n) {
  int i = blockIdx.x * blockDim.x + threadIdx.x;
  if (i < n) p[i] = 0;
}

// ---------------- router: fp32 logits, first-index argmax, bucket tokens ----
__global__ __launch_bounds__(64) void router_kernel(const float* __restrict__ ca,
                                                    const float* __restrict__ gw,
                                                    const float* __restrict__ gb,
                                                    int* __restrict__ cursors,
                                                    int* __restrict__ list) {
  int t = blockIdx.x;
  int lane = threadIdx.x;
  const float* x = ca + (long)t * kH;
  float acc[kE];
#pragma unroll
  for (int e = 0; e < kE; e++) acc[e] = 0.0f;
  for (int h = lane; h < kH; h += 64) {
    float xv = x[h];
    const float* gr = gw + (long)h * kE;
#pragma unroll
    for (int e = 0; e < kE; e++) acc[e] += xv * gr[e];
  }
#pragma unroll
  for (int e = 0; e < kE; e++)
    for (int o = 32; o; o >>= 1) acc[e] += __shfl_down(acc[e], o);
  if (lane == 0) {
    int best = 0;
    float bv = acc[0] + gb[0];
    for (int e = 1; e < kE; e++) {
      float v = acc[e] + gb[e];
      if (v > bv) { bv = v; best = e; }  // strict > == first-index argmax
    }
    int slot = atomicAdd(&cursors[best], 1);
    list[best * kTok + slot] = t;
  }
}

// ---------------- m97-style fp16 MFMA GEMM ----------------
// C[M,N] = epilogue(A[M,K] @ B[N,K]^T); B is [N][K] k-contiguous.
// LDS layout [q][row][8] f16 so global_load_lds (base+lane*16) lands contiguously
// AND fragment ds_read_b128 is only 2-way bank aliased (free).
struct GemmP {
  const f16* A; long a_row, a_z1, a_z2;
  const f16* Bm; long b_nstr, b_z1, b_z2;
  float* Cf; f16* Ch; long c_row, c_z1, c_z2; int c_tr;
  const float* bias; long bias_z;
  const float* res; long res_row, res_z1, res_z2;
  float alpha; int gelu;
  int M, N, K, zdiv;
  const int* glist; const int* cnt;  // expert-gather mode: z = expert
};

template <int TM, int TN, int WR, int TI, int TJ>
__global__ __launch_bounds__(256) void gemm_t(GemmP p) {
  __shared__ f16 As[4 * TM * 8];
  __shared__ f16 Bs[4 * TN * 8];
  int z = blockIdx.z;
  long aoff = 0, boff = 0, coff = 0, roff = 0, biasoff = 0;
  const int* gl = nullptr;
  int Meff = p.M;
  if (p.glist) {
    Meff = p.cnt[z];
    gl = p.glist + (long)z * kTok;
    boff = (long)z * p.b_z2;
    biasoff = (long)z * p.bias_z;
  } else {
    int z1 = z / p.zdiv, z2 = z % p.zdiv;
    aoff = (long)z1 * p.a_z1 + (long)z2 * p.a_z2;
    boff = (long)z1 * p.b_z1 + (long)z2 * p.b_z2;
    coff = (long)z1 * p.c_z1 + (long)z2 * p.c_z2;
    roff = (long)z1 * p.res_z1 + (long)z2 * p.res_z2;
  }
  int m0 = blockIdx.y * TM;
  if (m0 >= Meff) return;
  int n0 = blockIdx.x * TN;
  int tid = threadIdx.x, lane = tid & 63, wave = tid >> 6;
  int wm = (wave % WR) * (TI * 16), wn = (wave / WR) * (TJ * 16);
  int q = lane >> 4, lo = lane & 15;

  constexpr int CA = TM * 4 / 256;  // 16B chunks per thread for A
  constexpr int CB = TN * 4 / 256;
  const f16* asrc[CA];
  const f16* bsrc[CB];
#pragma unroll
  for (int s = 0; s < CA; s++) {
    int c = s * 256 + tid;
    int qa = c / TM, ra = c % TM;
    int row = m0 + ra;
    if (gl) row = gl[row < Meff ? row : Meff - 1];  // clamp: garbage rows never stored
    asrc[s] = p.A + aoff + (long)row * p.a_row + qa * 8;
  }
#pragma unroll
  for (int s = 0; s < CB; s++) {
    int c = s * 256 + tid;
    int qb = c / TN, rb = c % TN;
    bsrc[s] = p.Bm + boff + (long)(n0 + rb) * p.b_nstr + qb * 8;
  }

  f32x4 acc[TI][TJ] = {};
  for (int k0 = 0; k0 < p.K; k0 += 32) {
#pragma unroll
    for (int s = 0; s < CA; s++) g2l16(asrc[s] + k0, &As[(s * 256 + tid) * 8]);
#pragma unroll
    for (int s = 0; s < CB; s++) g2l16(bsrc[s] + k0, &Bs[(s * 256 + tid) * 8]);
    __syncthreads();
    half8 af[TI], bf[TJ];
#pragma unroll
    for (int i = 0; i < TI; i++) af[i] = *(const half8*)&As[(q * TM + wm + i * 16 + lo) * 8];
#pragma unroll
    for (int j = 0; j < TJ; j++) bf[j] = *(const half8*)&Bs[(q * TN + wn + j * 16 + lo) * 8];
#pragma unroll
    for (int i = 0; i < TI; i++)
#pragma unroll
      for (int j = 0; j < TJ; j++)
        acc[i][j] = __builtin_amdgcn_mfma_f32_16x16x32_f16(af[i], bf[j], acc[i][j], 0, 0, 0);
    __syncthreads();
  }

#pragma unroll
  for (int i = 0; i < TI; i++) {
#pragma unroll
    for (int j = 0; j < TJ; j++) {
      int col = n0 + wn + j * 16 + lo;
      if (p.c_tr) {  // transposed f16 store: 4 consecutive rows -> one 8B store
        int row0 = m0 + wm + i * 16 + q * 4;
        union { f16 h[4]; uint2 u; } o;
#pragma unroll
        for (int r = 0; r < 4; r++) {
          float v = acc[i][j][r];
          if (p.bias) v += p.bias[biasoff + col];
          v *= p.alpha;
          o.h[r] = (f16)v;
        }
        *(uint2*)&p.Ch[coff + (long)col * p.c_row + row0] = o.u;
      } else {
#pragma unroll
        for (int r = 0; r < 4; r++) {
          int row = m0 + wm + i * 16 + q * 4 + r;
          if (row < Meff) {
            long rr = gl ? (long)gl[row] : (long)row;
            float v = acc[i][j][r];
            if (p.bias) v += p.bias[biasoff + col];
            v *= p.alpha;
            if (p.res) v += p.res[roff + rr * p.res_row + col];
            if (p.gelu) v = 0.5f * v * (1.0f + erff(v * 0.70710678118654752f));
            if (p.Cf) p.Cf[coff + rr * p.c_row + col] = v;
            else p.Ch[coff + rr * p.c_row + col] = (f16)v;
          }
        }
      }
    }
  }
}

extern "C" void kernel_launch(void* const* d_in, const int* in_sizes, int n_in,
                              void* d_out, int out_size, void* d_ws, size_t ws_size,
                              hipStream_t stream) {
  const float* concated = (const float*)d_in[0];
  const float* gen      = (const float*)d_in[1];
  const float* mask     = (const float*)d_in[2];
  const float* ln_g     = (const float*)d_in[3];
  const float* ln_b     = (const float*)d_in[4];
  const float* wq = (const float*)d_in[5];  const float* bq = (const float*)d_in[6];
  const float* wk = (const float*)d_in[7];  const float* bk = (const float*)d_in[8];
  const float* wv = (const float*)d_in[9];  const float* bv = (const float*)d_in[10];
  const float* wo = (const float*)d_in[11]; const float* bo = (const float*)d_in[12];
  const float* gw = (const float*)d_in[13]; const float* gb = (const float*)d_in[14];
  const float* w1 = (const float*)d_in[15]; const float* b1 = (const float*)d_in[16];
  const float* w2 = (const float*)d_in[17]; const float* b2 = (const float*)d_in[18];
  float* out = (float*)d_out;

  size_t off = 0;
  auto alloc = [&](size_t bytes) -> void* {
    void* p = (char*)d_ws + off;
    off += (bytes + 255) & ~(size_t)255;
    return p;
  };
  f16* wq_t  = (f16*)alloc((size_t)kH * kH * 2);       // [N][K]
  f16* wk_t  = (f16*)alloc((size_t)kH * kH * 2);
  f16* wv_t  = (f16*)alloc((size_t)kH * kH * 2);
  f16* wo_t  = (f16*)alloc((size_t)kH * kH * 2);
  f16* w1_t  = (f16*)alloc((size_t)kE * kH * kDFF * 2);  // [E][DFF][H]
  f16* w2_t  = (f16*)alloc((size_t)kE * kDFF * kH * 2);  // [E][H][DFF]
  f16* lnc_h = (f16*)alloc((size_t)kB * kSK * kH * 2);
  f16* lng_h = (f16*)alloc((size_t)kTok * kH * 2);
  f16* q_h   = (f16*)alloc((size_t)kTok * kH * 2);
  f16* k_h   = (f16*)alloc((size_t)kB * kSK * kH * 2);
  f16* v_t   = (f16*)alloc((size_t)kB * kSK * kH * 2);   // [b][h][d][sk]
  f16* sc_h  = (f16*)alloc((size_t)kB * kHeads * kSQ * kSK * 2);
  f16* ctx_h = (f16*)alloc((size_t)kTok * kH * 2);
  float* ca_f   = (float*)alloc((size_t)kTok * kH * 4);
  float* lnca_f = (float*)alloc((size_t)kTok * kH * 4);
  f16* lnca_h   = (f16*)alloc((size_t)kTok * kH * 2);
  f16* h1_h     = (f16*)alloc((size_t)kTok * kDFF * 2);
  int* cnt_d    = (int*)alloc(kE * 4);
  int* list_d   = (int*)alloc((size_t)kE * kTok * 4);

  // ---- weight transpose-convert fp32 [K][N] -> fp16 [N][K] ----
  tr_f2h<<<dim3(32, 32, 1), 256, 0, stream>>>(wq, wq_t, kH, kH);
  tr_f2h<<<dim3(32, 32, 1), 256, 0, stream>>>(wk, wk_t, kH, kH);
  tr_f2h<<<dim3(32, 32, 1), 256, 0, stream>>>(wv, wv_t, kH, kH);
  tr_f2h<<<dim3(32, 32, 1), 256, 0, stream>>>(wo, wo_t, kH, kH);
  tr_f2h<<<dim3(kDFF / 32, kH / 32, kE), 256, 0, stream>>>(w1, w1_t, kH, kDFF);
  tr_f2h<<<dim3(kH / 32, kDFF / 32, kE), 256, 0, stream>>>(w2, w2_t, kDFF, kH);

  // ---- LayerNorms of inputs ----
  ln_kernel<<<kB * kSK, 256, 0, stream>>>(concated, ln_g, ln_b, lnc_h, nullptr, kB * kSK);
  ln_kernel<<<kTok, 256, 0, stream>>>(gen, ln_g, ln_b, lng_h, nullptr, kTok);

  // ---- Q projection (scale 0.125 folded), config B for grid width ----
  {
    GemmP p{}; p.A = lng_h; p.a_row = kH;
    p.Bm = wq_t; p.b_nstr = kH;
    p.Ch = q_h; p.c_row = kH; p.bias = bq; p.alpha = 0.125f;
    p.M = kTok; p.N = kH; p.K = kH; p.zdiv = 1;
    gemm_t<128, 64, 4, 2, 4><<<dim3(kH / 64, kTok / 128, 1), 256, 0, stream>>>(p);
  }
  // ---- K projection ----
  {
    GemmP p{}; p.A = lnc_h; p.a_row = kH;
    p.Bm = wk_t; p.b_nstr = kH;
    p.Ch = k_h; p.c_row = kH; p.bias = bk; p.alpha = 1.0f;
    p.M = kB * kSK; p.N = kH; p.K = kH; p.zdiv = 1;
    gemm_t<128, 128, 2, 4, 4><<<dim3(kH / 128, kB * kSK / 128, 1), 256, 0, stream>>>(p);
  }
  // ---- V projection, transposed store into v_t[b][h][d][sk]; z = batch ----
  {
    GemmP p{}; p.A = lnc_h; p.a_row = kH; p.a_z1 = (long)kSK * kH; p.a_z2 = 0;
    p.Bm = wv_t; p.b_nstr = kH; p.b_z1 = 0; p.b_z2 = 0;
    p.Ch = v_t; p.c_row = kSK; p.c_z1 = (long)kH * kSK; p.c_z2 = 0; p.c_tr = 1;
    p.bias = bv; p.alpha = 1.0f;
    p.M = kSK; p.N = kH; p.K = kH; p.zdiv = 1;
    gemm_t<128, 128, 2, 4, 4><<<dim3(kH / 128, kSK / 128, kB), 256, 0, stream>>>(p);
  }
  // ---- scores[b,h] = q @ k^T + mask (fp16 out) ----
  {
    GemmP p{}; p.A = q_h; p.a_row = kH; p.a_z1 = (long)kSQ * kH; p.a_z2 = 64;
    p.Bm = k_h; p.b_nstr = kH; p.b_z1 = (long)kSK * kH; p.b_z2 = 64;
    p.Ch = sc_h; p.c_row = kSK; p.c_z1 = (long)kHeads * kSQ * kSK; p.c_z2 = (long)kSQ * kSK;
    p.res = mask; p.res_row = kSK; p.res_z1 = (long)kSQ * kSK; p.res_z2 = 0;
    p.alpha = 1.0f; p.M = kSQ; p.N = kSK; p.K = 64; p.zdiv = kHeads;
    gemm_t<128, 128, 2, 4, 4><<<dim3(kSK / 128, kSQ / 128, kB * kHeads), 256, 0, stream>>>(p);
  }
  softmax_kernel<<<kB * kHeads * kSQ, 256, 0, stream>>>(sc_h);
  // ---- ctx[b,h] = probs @ v_t[b,h]^T (N=64) ----
  {
    GemmP p{}; p.A = sc_h; p.a_row = kSK; p.a_z1 = (long)kHeads * kSQ * kSK; p.a_z2 = (long)kSQ * kSK;
    p.Bm = v_t; p.b_nstr = kSK; p.b_z1 = (long)kH * kSK; p.b_z2 = (long)64 * kSK;
    p.Ch = ctx_h; p.c_row = kH; p.c_z1 = (long)kSQ * kH; p.c_z2 = 64;
    p.alpha = 1.0f; p.M = kSQ; p.N = 64; p.K = kSK; p.zdiv = kHeads;
    gemm_t<128, 64, 4, 2, 4><<<dim3(1, kSQ / 128, kB * kHeads), 256, 0, stream>>>(p);
  }
  // ---- ca_out = ctx @ wo^T + bo + gen (fp32 out) ----
  {
    GemmP p{}; p.A = ctx_h; p.a_row = kH;
    p.Bm = wo_t; p.b_nstr = kH;
    p.Cf = ca_f; p.c_row = kH; p.bias = bo;
    p.res = gen; p.res_row = kH;
    p.alpha = 1.0f; p.M = kTok; p.N = kH; p.K = kH; p.zdiv = 1;
    gemm_t<128, 64, 4, 2, 4><<<dim3(kH / 64, kTok / 128, 1), 256, 0, stream>>>(p);
  }
  // ---- ln_ca (fp32 + fp16) ----
  ln_kernel<<<kTok, 256, 0, stream>>>(ca_f, ln_g, ln_b, lnca_h, lnca_f, kTok);
  // ---- router + expert bucketing ----
  zero_kernel<<<1, 64, 0, stream>>>(cnt_d, kE);
  router_kernel<<<kTok, 64, 0, stream>>>(ca_f, gw, gb, cnt_d, list_d);
  // ---- FFN1: h1 = gelu(ln_ca @ w1[e] + b1[e]) ----
  {
    GemmP p{}; p.A = lnca_h; p.a_row = kH;
    p.Bm = w1_t; p.b_nstr = kH; p.b_z2 = (long)kH * kDFF;
    p.Ch = h1_h; p.c_row = kDFF; p.bias = b1; p.bias_z = kDFF;
    p.alpha = 1.0f; p.gelu = 1; p.M = kTok; p.N = kDFF; p.K = kH; p.zdiv = 1;
    p.glist = list_d; p.cnt = cnt_d;
    gemm_t<128, 128, 2, 4, 4><<<dim3(kDFF / 128, kTok / 128, kE), 256, 0, stream>>>(p);
  }
  // ---- FFN2: out = h1 @ w2[e] + b2[e] + ln_ca (fp32, scatter to d_out) ----
  {
    GemmP p{}; p.A = h1_h; p.a_row = kDFF;
    p.Bm = w2_t; p.b_nstr = kDFF; p.b_z2 = (long)kDFF * kH;
    p.Cf = out; p.c_row = kH; p.bias = b2; p.bias_z = kH;
    p.res = lnca_f; p.res_row = kH;
    p.alpha = 1.0f; p.M = kTok; p.N = kH; p.K = kDFF; p.zdiv = 1;
    p.glist = list_d; p.cnt = cnt_d;
    gemm_t<128, 64, 4, 2, 4><<<dim3(kH / 64, kTok / 128, kE), 256, 0, stream>>>(p);
  }
}

// Round 3
// 849.858 us; speedup vs baseline: 1.3520x; 1.3520x over previous
//
#include <hip/hip_runtime.h>
#include <stdint.h>
#include <stddef.h>

typedef _Float16 f16;
typedef _Float16 half8 __attribute__((ext_vector_type(8)));
typedef float f32x4 __attribute__((ext_vector_type(4)));

constexpr int kB = 4, kSQ = 512, kSK = 1024, kH = 1024, kHeads = 16, kE = 8, kDFF = 4096;
constexpr int kTok = kB * kSQ;  // 2048 gen tokens

// async global->LDS, 16B per lane; LDS dest must be wave-uniform base + lane*16
__device__ __forceinline__ void g2l16(const f16* g, f16* l) {
  __builtin_amdgcn_global_load_lds((const __attribute__((address_space(1))) uint32_t*)g,
                                   (__attribute__((address_space(3))) uint32_t*)l, 16, 0, 0);
}

// ---------------- transpose + fp32->fp16: dst[C][R] = (f16)src[R][C], batched over z
__global__ __launch_bounds__(256) void tr_f2h(const float* __restrict__ src,
                                              f16* __restrict__ dst, int R, int C) {
  __shared__ float t[32][33];
  long zo = (long)blockIdx.z * R * C;
  int r0 = blockIdx.y * 32, c0 = blockIdx.x * 32;
  int tr = threadIdx.x >> 3, tc = (threadIdx.x & 7) << 2;
  float4 v = *(const float4*)(src + zo + (long)(r0 + tr) * C + c0 + tc);
  t[tr][tc] = v.x; t[tr][tc + 1] = v.y; t[tr][tc + 2] = v.z; t[tr][tc + 3] = v.w;
  __syncthreads();
  union { f16 h[4]; uint2 u; } o;
  o.h[0] = (f16)t[tc + 0][tr]; o.h[1] = (f16)t[tc + 1][tr];
  o.h[2] = (f16)t[tc + 2][tr]; o.h[3] = (f16)t[tc + 3][tr];
  *(uint2*)(dst + zo + (long)(c0 + tr) * R + r0 + tc) = o.u;
}

// ---------------- LayerNorm over H=1024, one block (256 thr) per row --------
__global__ __launch_bounds__(256) void ln_kernel(const float* __restrict__ x,
                                                 const float* __restrict__ g,
                                                 const float* __restrict__ b,
                                                 f16* __restrict__ oh, float* __restrict__ of,
                                                 int rows) {
  int row = blockIdx.x;
  if (row >= rows) return;
  int tid = threadIdx.x;
  const float* xr = x + (long)row * kH;
  float4 v = *(const float4*)(xr + tid * 4);
  float s = v.x + v.y + v.z + v.w;
  float s2 = v.x * v.x + v.y * v.y + v.z * v.z + v.w * v.w;
  __shared__ float red[8];
  for (int o = 32; o; o >>= 1) { s += __shfl_down(s, o); s2 += __shfl_down(s2, o); }
  int wv = tid >> 6, lane = tid & 63;
  if (lane == 0) { red[wv] = s; red[4 + wv] = s2; }
  __syncthreads();
  if (tid == 0) {
    red[0] = red[0] + red[1] + red[2] + red[3];
    red[4] = red[4] + red[5] + red[6] + red[7];
  }
  __syncthreads();
  float mean = red[0] * (1.0f / kH);
  float var = red[4] * (1.0f / kH) - mean * mean;
  float rs = rsqrtf(var + 1e-6f);
  float4 gv = *(const float4*)(g + tid * 4);
  float4 bv = *(const float4*)(b + tid * 4);
  float y0 = (v.x - mean) * rs * gv.x + bv.x;
  float y1 = (v.y - mean) * rs * gv.y + bv.y;
  float y2 = (v.z - mean) * rs * gv.z + bv.z;
  float y3 = (v.w - mean) * rs * gv.w + bv.w;
  long base = (long)row * kH + tid * 4;
  if (oh) {
    union { f16 h[4]; uint2 u; } o;
    o.h[0] = (f16)y0; o.h[1] = (f16)y1; o.h[2] = (f16)y2; o.h[3] = (f16)y3;
    *(uint2*)(oh + base) = o.u;
  }
  if (of) { float4 o4 = {y0, y1, y2, y3}; *(float4*)(of + base) = o4; }
}

// ---------------- row softmax over SK=1024, in place, fp16 ----------------
__global__ __launch_bounds__(256) void softmax_kernel(f16* __restrict__ sc) {
  long row = blockIdx.x;
  f16* p = sc + row * kSK;
  int tid = threadIdx.x;
  union { f16 h[4]; uint2 u; } lv;
  lv.u = *(uint2*)(p + tid * 4);
  float v0 = (float)lv.h[0], v1 = (float)lv.h[1], v2 = (float)lv.h[2], v3 = (float)lv.h[3];
  __shared__ float red[8];
  float mx = fmaxf(fmaxf(v0, v1), fmaxf(v2, v3));
  for (int o = 32; o; o >>= 1) mx = fmaxf(mx, __shfl_down(mx, o));
  int wv = tid >> 6, lane = tid & 63;
  if (lane == 0) red[wv] = mx;
  __syncthreads();
  if (tid == 0) red[0] = fmaxf(fmaxf(red[0], red[1]), fmaxf(red[2], red[3]));
  __syncthreads();
  mx = red[0];
  float e0 = __expf(v0 - mx), e1 = __expf(v1 - mx), e2 = __expf(v2 - mx), e3 = __expf(v3 - mx);
  float s = e0 + e1 + e2 + e3;
  for (int o = 32; o; o >>= 1) s += __shfl_down(s, o);
  if (lane == 0) red[4 + wv] = s;
  __syncthreads();
  if (tid == 0) red[4] = red[4] + red[5] + red[6] + red[7];
  __syncthreads();
  float inv = 1.0f / red[4];
  lv.h[0] = (f16)(e0 * inv); lv.h[1] = (f16)(e1 * inv);
  lv.h[2] = (f16)(e2 * inv); lv.h[3] = (f16)(e3 * inv);
  *(uint2*)(p + tid * 4) = lv.u;
}

__global__ void zero_kernel(int* __restrict__ p, int n) {
  int i = blockIdx.x * blockDim.x + threadIdx.x;
  if (i < n) p[i] = 0;
}

// ---------------- router: fp32 logits, first-index argmax, bucket tokens ----
__global__ __launch_bounds__(64) void router_kernel(const float* __restrict__ ca,
                                                    const float* __restrict__ gw,
                                                    const float* __restrict__ gb,
                                                    int* __restrict__ cursors,
                                                    int* __restrict__ list,
                                                    int* __restrict__ eid) {
  int t = blockIdx.x;
  int lane = threadIdx.x;
  const float* x = ca + (long)t * kH;
  float acc[kE];
#pragma unroll
  for (int e = 0; e < kE; e++) acc[e] = 0.0f;
  for (int h = lane; h < kH; h += 64) {
    float xv = x[h];
    const float* gr = gw + (long)h * kE;
#pragma unroll
    for (int e = 0; e < kE; e++) acc[e] += xv * gr[e];
  }
#pragma unroll
  for (int e = 0; e < kE; e++)
    for (int o = 32; o; o >>= 1) acc[e] += __shfl_down(acc[e], o);
  if (lane == 0) {
    int best = 0;
    float bv = acc[0] + gb[0];
    for (int e = 1; e < kE; e++) {
      float v = acc[e] + gb[e];
      if (v > bv) { bv = v; best = e; }  // strict > == first-index argmax
    }
    int slot = atomicAdd(&cursors[best], 1);
    list[best * kTok + slot] = t;
    eid[t] = best;
  }
}

// ---------------- FFN2 init: out[t] = lnca[t] + b2[eid[t]] (atomic GEMM adds on top)
__global__ __launch_bounds__(256) void ffn2_init(const float* __restrict__ lnca,
                                                 const float* __restrict__ b2,
                                                 const int* __restrict__ eid,
                                                 float* __restrict__ out) {
  int t = blockIdx.x;
  int i = threadIdx.x * 4;
  int e = eid[t];
  float4 v = *(const float4*)(lnca + (long)t * kH + i);
  float4 b = *(const float4*)(b2 + (long)e * kH + i);
  float4 o = {v.x + b.x, v.y + b.y, v.z + b.z, v.w + b.w};
  *(float4*)(out + (long)t * kH + i) = o;
}

// ---------------- 64x64-tile fp16 MFMA GEMM, BK=64, global_load_lds staging --
// C[M,N] = epilogue(A[M,K] @ B[N,K]^T); B is [N][K] k-contiguous.
// LDS chunk layout: chunk c holds (kq=c/64, row=c%64) 16B; g2l dest = base+lane*16.
struct GemmP {
  const f16* A; long a_row, a_z1, a_z2;
  const f16* Bm; long b_nstr, b_z1, b_z2;
  float* Cf; f16* Ch; long c_row, c_z1, c_z2; int c_tr;
  const float* bias; long bias_z;
  const float* res; long res_row, res_z1, res_z2;
  float alpha; int gelu; int atomic; int ksplit;
  int M, N, K, zdiv;
  const int* glist; const int* cnt;  // expert-gather mode: z = expert
};

__global__ __launch_bounds__(256) void gemm_t(GemmP p) {
  __shared__ f16 As[64 * 64];
  __shared__ f16 Bs[64 * 64];
  int z = blockIdx.z;
  int kb = 0, kEnd = p.K;
  if (p.ksplit > 1) {
    int kc = p.K / p.ksplit;
    kb = (z % p.ksplit) * kc;
    kEnd = kb + kc;
    z /= p.ksplit;
  }
  long aoff = 0, boff = 0, coff = 0, roff = 0, biasoff = 0;
  const int* gl = nullptr;
  int Meff = p.M;
  if (p.glist) {
    Meff = p.cnt[z];
    gl = p.glist + (long)z * kTok;
    boff = (long)z * p.b_z2;
    biasoff = (long)z * p.bias_z;
  } else {
    int z1 = z / p.zdiv, z2 = z % p.zdiv;
    aoff = (long)z1 * p.a_z1 + (long)z2 * p.a_z2;
    boff = (long)z1 * p.b_z1 + (long)z2 * p.b_z2;
    coff = (long)z1 * p.c_z1 + (long)z2 * p.c_z2;
    roff = (long)z1 * p.res_z1 + (long)z2 * p.res_z2;
  }
  int m0 = blockIdx.y * 64;
  if (m0 >= Meff) return;
  int n0 = blockIdx.x * 64;
  int tid = threadIdx.x, lane = tid & 63, wave = tid >> 6;
  int wm = (wave & 1) * 32, wn = (wave >> 1) * 32;
  int q = lane >> 4, lo = lane & 15;

  // 2 chunks each for A and B per thread (64 rows x 8 kq-groups = 512 chunks)
  const f16* asrc[2];
  const f16* bsrc[2];
#pragma unroll
  for (int s = 0; s < 2; s++) {
    int c = s * 256 + tid;
    int kq = c >> 6, ra = c & 63;
    int row = m0 + ra;
    if (gl) row = gl[row < Meff ? row : Meff - 1];  // clamp: garbage rows never stored
    asrc[s] = p.A + aoff + (long)row * p.a_row + kq * 8;
    bsrc[s] = p.Bm + boff + (long)(n0 + ra) * p.b_nstr + kq * 8;
  }

  f32x4 acc[2][2] = {};
  for (int k0 = kb; k0 < kEnd; k0 += 64) {
#pragma unroll
    for (int s = 0; s < 2; s++) g2l16(asrc[s] + k0, &As[(s * 256 + tid) * 8]);
#pragma unroll
    for (int s = 0; s < 2; s++) g2l16(bsrc[s] + k0, &Bs[(s * 256 + tid) * 8]);
    __syncthreads();
    half8 af[2][2], bf[2][2];
#pragma unroll
    for (int kk = 0; kk < 2; kk++) {
#pragma unroll
      for (int i = 0; i < 2; i++) {
        af[kk][i] = *(const half8*)&As[((kk * 4 + q) * 64 + wm + i * 16 + lo) * 8];
        bf[kk][i] = *(const half8*)&Bs[((kk * 4 + q) * 64 + wn + i * 16 + lo) * 8];
      }
    }
#pragma unroll
    for (int kk = 0; kk < 2; kk++)
#pragma unroll
      for (int i = 0; i < 2; i++)
#pragma unroll
        for (int j = 0; j < 2; j++)
          acc[i][j] = __builtin_amdgcn_mfma_f32_16x16x32_f16(af[kk][i], bf[kk][j], acc[i][j], 0, 0, 0);
    __syncthreads();
  }

#pragma unroll
  for (int i = 0; i < 2; i++) {
#pragma unroll
    for (int j = 0; j < 2; j++) {
      int col = n0 + wn + j * 16 + lo;
      if (p.c_tr) {  // transposed f16 store: 4 consecutive rows -> one 8B store
        int row0 = m0 + wm + i * 16 + q * 4;
        union { f16 h[4]; uint2 u; } o;
#pragma unroll
        for (int r = 0; r < 4; r++) {
          float v = acc[i][j][r];
          if (p.bias) v += p.bias[biasoff + col];
          v *= p.alpha;
          o.h[r] = (f16)v;
        }
        *(uint2*)&p.Ch[coff + (long)col * p.c_row + row0] = o.u;
      } else {
#pragma unroll
        for (int r = 0; r < 4; r++) {
          int row = m0 + wm + i * 16 + q * 4 + r;
          if (row < Meff) {
            long rr = gl ? (long)gl[row] : (long)row;
            float v = acc[i][j][r];
            if (p.bias) v += p.bias[biasoff + col];
            v *= p.alpha;
            if (p.res) v += p.res[roff + rr * p.res_row + col];
            if (p.gelu) v = 0.5f * v * (1.0f + erff(v * 0.70710678118654752f));
            long ci = coff + rr * p.c_row + col;
            if (p.atomic) atomicAdd(&p.Cf[ci], v);
            else if (p.Cf) p.Cf[ci] = v;
            else p.Ch[ci] = (f16)v;
          }
        }
      }
    }
  }
}

extern "C" void kernel_launch(void* const* d_in, const int* in_sizes, int n_in,
                              void* d_out, int out_size, void* d_ws, size_t ws_size,
                              hipStream_t stream) {
  const float* concated = (const float*)d_in[0];
  const float* gen      = (const float*)d_in[1];
  const float* mask     = (const float*)d_in[2];
  const float* ln_g     = (const float*)d_in[3];
  const float* ln_b     = (const float*)d_in[4];
  const float* wq = (const float*)d_in[5];  const float* bq = (const float*)d_in[6];
  const float* wk = (const float*)d_in[7];  const float* bk = (const float*)d_in[8];
  const float* wv = (const float*)d_in[9];  const float* bv = (const float*)d_in[10];
  const float* wo = (const float*)d_in[11]; const float* bo = (const float*)d_in[12];
  const float* gw = (const float*)d_in[13]; const float* gb = (const float*)d_in[14];
  const float* w1 = (const float*)d_in[15]; const float* b1 = (const float*)d_in[16];
  const float* w2 = (const float*)d_in[17]; const float* b2 = (const float*)d_in[18];
  float* out = (float*)d_out;

  size_t off = 0;
  auto alloc = [&](size_t bytes) -> void* {
    void* p = (char*)d_ws + off;
    off += (bytes + 255) & ~(size_t)255;
    return p;
  };
  f16* wq_t  = (f16*)alloc((size_t)kH * kH * 2);       // [N][K]
  f16* wk_t  = (f16*)alloc((size_t)kH * kH * 2);
  f16* wv_t  = (f16*)alloc((size_t)kH * kH * 2);
  f16* wo_t  = (f16*)alloc((size_t)kH * kH * 2);
  f16* w1_t  = (f16*)alloc((size_t)kE * kH * kDFF * 2);  // [E][DFF][H]
  f16* w2_t  = (f16*)alloc((size_t)kE * kDFF * kH * 2);  // [E][H][DFF]
  f16* lnc_h = (f16*)alloc((size_t)kB * kSK * kH * 2);
  f16* lng_h = (f16*)alloc((size_t)kTok * kH * 2);
  f16* q_h   = (f16*)alloc((size_t)kTok * kH * 2);
  f16* k_h   = (f16*)alloc((size_t)kB * kSK * kH * 2);
  f16* v_t   = (f16*)alloc((size_t)kB * kSK * kH * 2);   // [b][h][d][sk]
  f16* sc_h  = (f16*)alloc((size_t)kB * kHeads * kSQ * kSK * 2);
  f16* ctx_h = (f16*)alloc((size_t)kTok * kH * 2);
  float* ca_f   = (float*)alloc((size_t)kTok * kH * 4);
  float* lnca_f = (float*)alloc((size_t)kTok * kH * 4);
  f16* lnca_h   = (f16*)alloc((size_t)kTok * kH * 2);
  f16* h1_h     = (f16*)alloc((size_t)kTok * kDFF * 2);
  int* cnt_d    = (int*)alloc(kE * 4);
  int* list_d   = (int*)alloc((size_t)kE * kTok * 4);
  int* eid_d    = (int*)alloc((size_t)kTok * 4);

  // ---- weight transpose-convert fp32 [K][N] -> fp16 [N][K] ----
  tr_f2h<<<dim3(32, 32, 1), 256, 0, stream>>>(wq, wq_t, kH, kH);
  tr_f2h<<<dim3(32, 32, 1), 256, 0, stream>>>(wk, wk_t, kH, kH);
  tr_f2h<<<dim3(32, 32, 1), 256, 0, stream>>>(wv, wv_t, kH, kH);
  tr_f2h<<<dim3(32, 32, 1), 256, 0, stream>>>(wo, wo_t, kH, kH);
  tr_f2h<<<dim3(kDFF / 32, kH / 32, kE), 256, 0, stream>>>(w1, w1_t, kH, kDFF);
  tr_f2h<<<dim3(kH / 32, kDFF / 32, kE), 256, 0, stream>>>(w2, w2_t, kDFF, kH);

  // ---- LayerNorms of inputs ----
  ln_kernel<<<kB * kSK, 256, 0, stream>>>(concated, ln_g, ln_b, lnc_h, nullptr, kB * kSK);
  ln_kernel<<<kTok, 256, 0, stream>>>(gen, ln_g, ln_b, lng_h, nullptr, kTok);

  // ---- Q projection (scale 0.125 folded) ----
  {
    GemmP p{}; p.A = lng_h; p.a_row = kH;
    p.Bm = wq_t; p.b_nstr = kH;
    p.Ch = q_h; p.c_row = kH; p.bias = bq; p.alpha = 0.125f;
    p.M = kTok; p.N = kH; p.K = kH; p.zdiv = 1;
    gemm_t<<<dim3(kH / 64, kTok / 64, 1), 256, 0, stream>>>(p);
  }
  // ---- K projection ----
  {
    GemmP p{}; p.A = lnc_h; p.a_row = kH;
    p.Bm = wk_t; p.b_nstr = kH;
    p.Ch = k_h; p.c_row = kH; p.bias = bk; p.alpha = 1.0f;
    p.M = kB * kSK; p.N = kH; p.K = kH; p.zdiv = 1;
    gemm_t<<<dim3(kH / 64, kB * kSK / 64, 1), 256, 0, stream>>>(p);
  }
  // ---- V projection, transposed store into v_t[b][h][d][sk]; z = batch ----
  {
    GemmP p{}; p.A = lnc_h; p.a_row = kH; p.a_z1 = (long)kSK * kH; p.a_z2 = 0;
    p.Bm = wv_t; p.b_nstr = kH; p.b_z1 = 0; p.b_z2 = 0;
    p.Ch = v_t; p.c_row = kSK; p.c_z1 = (long)kH * kSK; p.c_z2 = 0; p.c_tr = 1;
    p.bias = bv; p.alpha = 1.0f;
    p.M = kSK; p.N = kH; p.K = kH; p.zdiv = 1;
    gemm_t<<<dim3(kH / 64, kSK / 64, kB), 256, 0, stream>>>(p);
  }
  // ---- scores[b,h] = q @ k^T + mask (fp16 out) ----
  {
    GemmP p{}; p.A = q_h; p.a_row = kH; p.a_z1 = (long)kSQ * kH; p.a_z2 = 64;
    p.Bm = k_h; p.b_nstr = kH; p.b_z1 = (long)kSK * kH; p.b_z2 = 64;
    p.Ch = sc_h; p.c_row = kSK; p.c_z1 = (long)kHeads * kSQ * kSK; p.c_z2 = (long)kSQ * kSK;
    p.res = mask; p.res_row = kSK; p.res_z1 = (long)kSQ * kSK; p.res_z2 = 0;
    p.alpha = 1.0f; p.M = kSQ; p.N = kSK; p.K = 64; p.zdiv = kHeads;
    gemm_t<<<dim3(kSK / 64, kSQ / 64, kB * kHeads), 256, 0, stream>>>(p);
  }
  softmax_kernel<<<kB * kHeads * kSQ, 256, 0, stream>>>(sc_h);
  // ---- ctx[b,h] = probs @ v_t[b,h]^T (N=64) ----
  {
    GemmP p{}; p.A = sc_h; p.a_row = kSK; p.a_z1 = (long)kHeads * kSQ * kSK; p.a_z2 = (long)kSQ * kSK;
    p.Bm = v_t; p.b_nstr = kSK; p.b_z1 = (long)kH * kSK; p.b_z2 = (long)64 * kSK;
    p.Ch = ctx_h; p.c_row = kH; p.c_z1 = (long)kSQ * kH; p.c_z2 = 64;
    p.alpha = 1.0f; p.M = kSQ; p.N = 64; p.K = kSK; p.zdiv = kHeads;
    gemm_t<<<dim3(1, kSQ / 64, kB * kHeads), 256, 0, stream>>>(p);
  }
  // ---- ca_out = ctx @ wo^T + bo + gen (fp32 out) ----
  {
    GemmP p{}; p.A = ctx_h; p.a_row = kH;
    p.Bm = wo_t; p.b_nstr = kH;
    p.Cf = ca_f; p.c_row = kH; p.bias = bo;
    p.res = gen; p.res_row = kH;
    p.alpha = 1.0f; p.M = kTok; p.N = kH; p.K = kH; p.zdiv = 1;
    gemm_t<<<dim3(kH / 64, kTok / 64, 1), 256, 0, stream>>>(p);
  }
  // ---- ln_ca (fp32 + fp16) ----
  ln_kernel<<<kTok, 256, 0, stream>>>(ca_f, ln_g, ln_b, lnca_h, lnca_f, kTok);
  // ---- router + expert bucketing ----
  zero_kernel<<<1, 64, 0, stream>>>(cnt_d, kE);
  router_kernel<<<kTok, 64, 0, stream>>>(ca_f, gw, gb, cnt_d, list_d, eid_d);
  // ---- FFN1: h1 = gelu(ln_ca @ w1[e] + b1[e]) ----
  {
    GemmP p{}; p.A = lnca_h; p.a_row = kH;
    p.Bm = w1_t; p.b_nstr = kH; p.b_z2 = (long)kH * kDFF;
    p.Ch = h1_h; p.c_row = kDFF; p.bias = b1; p.bias_z = kDFF;
    p.alpha = 1.0f; p.gelu = 1; p.M = kTok; p.N = kDFF; p.K = kH; p.zdiv = 1;
    p.glist = list_d; p.cnt = cnt_d;
    gemm_t<<<dim3(kDFF / 64, kTok / 64, kE), 256, 0, stream>>>(p);
  }
  // ---- FFN2: out = h1 @ w2[e] (+ b2 + lnca via init), split-K x4, atomic fp32 ----
  ffn2_init<<<kTok, 256, 0, stream>>>(lnca_f, b2, eid_d, out);
  {
    GemmP p{}; p.A = h1_h; p.a_row = kDFF;
    p.Bm = w2_t; p.b_nstr = kDFF; p.b_z2 = (long)kDFF * kH;
    p.Cf = out; p.c_row = kH;
    p.alpha = 1.0f; p.atomic = 1; p.ksplit = 4;
    p.M = kTok; p.N = kH; p.K = kDFF; p.zdiv = 1;
    p.glist = list_d; p.cnt = cnt_d;
    gemm_t<<<dim3(kH / 64, kTok / 64, kE * 4), 256, 0, stream>>>(p);
  }
}

// Round 4
// 800.028 us; speedup vs baseline: 1.4362x; 1.0623x over previous
//
#include <hip/hip_runtime.h>
#include <stdint.h>
#include <stddef.h>

typedef _Float16 f16;
typedef _Float16 half8 __attribute__((ext_vector_type(8)));
typedef float f32x4 __attribute__((ext_vector_type(4)));

constexpr int kB = 4, kSQ = 512, kSK = 1024, kH = 1024, kHeads = 16, kE = 8, kDFF = 4096;
constexpr int kTok = kB * kSQ;  // 2048 gen tokens

// async global->LDS, 16B per lane; LDS dest must be wave-uniform base + lane*16
__device__ __forceinline__ void g2l16(const f16* g, f16* l) {
  __builtin_amdgcn_global_load_lds((const __attribute__((address_space(1))) uint32_t*)g,
                                   (__attribute__((address_space(3))) uint32_t*)l, 16, 0, 0);
}

// ---------------- transpose + fp32->fp16: dst[C][R] = (f16)src[R][C], batched over z
__global__ __launch_bounds__(256) void tr_f2h(const float* __restrict__ src,
                                              f16* __restrict__ dst, int R, int C) {
  __shared__ float t[32][33];
  long zo = (long)blockIdx.z * R * C;
  int r0 = blockIdx.y * 32, c0 = blockIdx.x * 32;
  int tr = threadIdx.x >> 3, tc = (threadIdx.x & 7) << 2;
  float4 v = *(const float4*)(src + zo + (long)(r0 + tr) * C + c0 + tc);
  t[tr][tc] = v.x; t[tr][tc + 1] = v.y; t[tr][tc + 2] = v.z; t[tr][tc + 3] = v.w;
  __syncthreads();
  union { f16 h[4]; uint2 u; } o;
  o.h[0] = (f16)t[tc + 0][tr]; o.h[1] = (f16)t[tc + 1][tr];
  o.h[2] = (f16)t[tc + 2][tr]; o.h[3] = (f16)t[tc + 3][tr];
  *(uint2*)(dst + zo + (long)(c0 + tr) * R + r0 + tc) = o.u;
}

// ---------------- LayerNorm over H=1024, one block (256 thr) per row --------
__global__ __launch_bounds__(256) void ln_kernel(const float* __restrict__ x,
                                                 const float* __restrict__ g,
                                                 const float* __restrict__ b,
                                                 f16* __restrict__ oh, float* __restrict__ of,
                                                 int rows) {
  int row = blockIdx.x;
  if (row >= rows) return;
  int tid = threadIdx.x;
  const float* xr = x + (long)row * kH;
  float4 v = *(const float4*)(xr + tid * 4);
  float s = v.x + v.y + v.z + v.w;
  float s2 = v.x * v.x + v.y * v.y + v.z * v.z + v.w * v.w;
  __shared__ float red[8];
  for (int o = 32; o; o >>= 1) { s += __shfl_down(s, o); s2 += __shfl_down(s2, o); }
  int wv = tid >> 6, lane = tid & 63;
  if (lane == 0) { red[wv] = s; red[4 + wv] = s2; }
  __syncthreads();
  if (tid == 0) {
    red[0] = red[0] + red[1] + red[2] + red[3];
    red[4] = red[4] + red[5] + red[6] + red[7];
  }
  __syncthreads();
  float mean = red[0] * (1.0f / kH);
  float var = red[4] * (1.0f / kH) - mean * mean;
  float rs = rsqrtf(var + 1e-6f);
  float4 gv = *(const float4*)(g + tid * 4);
  float4 bv = *(const float4*)(b + tid * 4);
  float y0 = (v.x - mean) * rs * gv.x + bv.x;
  float y1 = (v.y - mean) * rs * gv.y + bv.y;
  float y2 = (v.z - mean) * rs * gv.z + bv.z;
  float y3 = (v.w - mean) * rs * gv.w + bv.w;
  long base = (long)row * kH + tid * 4;
  if (oh) {
    union { f16 h[4]; uint2 u; } o;
    o.h[0] = (f16)y0; o.h[1] = (f16)y1; o.h[2] = (f16)y2; o.h[3] = (f16)y3;
    *(uint2*)(oh + base) = o.u;
  }
  if (of) { float4 o4 = {y0, y1, y2, y3}; *(float4*)(of + base) = o4; }
}

__global__ void zero_kernel(int* __restrict__ p, int n) {
  int i = blockIdx.x * blockDim.x + threadIdx.x;
  if (i < n) p[i] = 0;
}

// ---------------- router: fp32 logits, first-index argmax, bucket tokens ----
__global__ __launch_bounds__(64) void router_kernel(const float* __restrict__ ca,
                                                    const float* __restrict__ gw,
                                                    const float* __restrict__ gb,
                                                    int* __restrict__ cursors,
                                                    int* __restrict__ list,
                                                    int* __restrict__ eid) {
  int t = blockIdx.x;
  int lane = threadIdx.x;
  const float* x = ca + (long)t * kH;
  float acc[kE];
#pragma unroll
  for (int e = 0; e < kE; e++) acc[e] = 0.0f;
  for (int h = lane; h < kH; h += 64) {
    float xv = x[h];
    const float* gr = gw + (long)h * kE;
#pragma unroll
    for (int e = 0; e < kE; e++) acc[e] += xv * gr[e];
  }
#pragma unroll
  for (int e = 0; e < kE; e++)
    for (int o = 32; o; o >>= 1) acc[e] += __shfl_down(acc[e], o);
  if (lane == 0) {
    int best = 0;
    float bv = acc[0] + gb[0];
    for (int e = 1; e < kE; e++) {
      float v = acc[e] + gb[e];
      if (v > bv) { bv = v; best = e; }  // strict > == first-index argmax
    }
    int slot = atomicAdd(&cursors[best], 1);
    list[best * kTok + slot] = t;
    eid[t] = best;
  }
}

// ---------------- FFN2 reduce: out = part0 + part1 + b2[eid] + lnca ----------
__global__ __launch_bounds__(256) void ffn2_reduce(const float* __restrict__ part,
                                                   const float* __restrict__ lnca,
                                                   const float* __restrict__ b2,
                                                   const int* __restrict__ eid,
                                                   float* __restrict__ out) {
  int t = blockIdx.x;
  int i = threadIdx.x * 4;
  int e = eid[t];
  long idx = (long)t * kH + i;
  float4 p0 = *(const float4*)(part + idx);
  float4 p1 = *(const float4*)(part + (long)kTok * kH + idx);
  float4 r  = *(const float4*)(lnca + idx);
  float4 bb = *(const float4*)(b2 + (long)e * kH + i);
  float4 o = {p0.x + p1.x + r.x + bb.x, p0.y + p1.y + r.y + bb.y,
              p0.z + p1.z + r.z + bb.z, p0.w + p1.w + r.w + bb.w};
  *(float4*)(out + idx) = o;
}

// ---------------- fused flash attention ----------------
// grid (SQ/64, B*Heads). Q a-frags from global; K,V tiles (64 keys) staged via
// global_load_lds; online softmax fp32; P->A-layout via padded wave-private LDS.
__global__ __launch_bounds__(256) void flash_kernel(const f16* __restrict__ q,
                                                    const f16* __restrict__ k,
                                                    const f16* __restrict__ v_t,
                                                    const float* __restrict__ mask,
                                                    f16* __restrict__ ctx) {
  __shared__ f16 Ks[64 * 64];
  __shared__ f16 Vs[64 * 64];
  __shared__ f16 Ps[4][16][72];  // pitch 72 (144B) breaks write conflicts
  int qt = blockIdx.x;
  int bh = blockIdx.y;
  int b = bh >> 4;
  int ho = (bh & 15) * 64;
  int tid = threadIdx.x, lane = tid & 63, wave = tid >> 6;
  int quad = lane >> 4, lo = lane & 15;

  // Q a-frags: A[m=lo][k=quad*8+j], k-halves kk*32
  long qg = ((long)b * kSQ + qt * 64 + wave * 16 + lo) * kH + ho;
  half8 aq0 = *(const half8*)(q + qg + quad * 8);
  half8 aq1 = *(const half8*)(q + qg + 32 + quad * 8);

  // staging pointers (tile 0); K chunk c=(kq=d-octet, key), V chunk c=(kq=key-octet, d)
  const f16* ksrc[2];
  const f16* vsrc[2];
#pragma unroll
  for (int s = 0; s < 2; s++) {
    int c = s * 256 + tid;
    int kq = c >> 6, r = c & 63;
    ksrc[s] = k + ((long)b * kSK + r) * kH + ho + kq * 8;
    vsrc[s] = v_t + ((long)bh * 64 + r) * kSK + kq * 8;
  }
  const float* maskp = mask + ((long)b * kSQ + qt * 64 + wave * 16 + quad * 4) * kSK;

  float m_s[4] = {-1e30f, -1e30f, -1e30f, -1e30f};
  float l_s[4] = {0.f, 0.f, 0.f, 0.f};
  f32x4 O[4] = {};  // [nt][r], cols ho+nt*16+lo, rows quad*4+r

  for (int kt = 0; kt < kSK / 64; kt++) {
    int sk0 = kt * 64;
#pragma unroll
    for (int s = 0; s < 2; s++) g2l16(ksrc[s] + (long)sk0 * kH, &Ks[(s * 256 + tid) * 8]);
#pragma unroll
    for (int s = 0; s < 2; s++) g2l16(vsrc[s] + sk0, &Vs[(s * 256 + tid) * 8]);
    __syncthreads();
    // S = Q @ K^T  (fp32 C-frags)
    f32x4 sf[4] = {};
#pragma unroll
    for (int nt = 0; nt < 4; nt++) {
      half8 bk0 = *(const half8*)&Ks[((0 * 4 + quad) * 64 + nt * 16 + lo) * 8];
      half8 bk1 = *(const half8*)&Ks[((1 * 4 + quad) * 64 + nt * 16 + lo) * 8];
      sf[nt] = __builtin_amdgcn_mfma_f32_16x16x32_f16(aq0, bk0, sf[nt], 0, 0, 0);
      sf[nt] = __builtin_amdgcn_mfma_f32_16x16x32_f16(aq1, bk1, sf[nt], 0, 0, 0);
    }
    // + mask
#pragma unroll
    for (int r = 0; r < 4; r++)
#pragma unroll
      for (int nt = 0; nt < 4; nt++)
        sf[nt][r] += maskp[(long)r * kSK + sk0 + nt * 16 + lo];
    // online softmax per row r
#pragma unroll
    for (int r = 0; r < 4; r++) {
      float mx = fmaxf(fmaxf(sf[0][r], sf[1][r]), fmaxf(sf[2][r], sf[3][r]));
      mx = fmaxf(mx, __shfl_xor(mx, 1));
      mx = fmaxf(mx, __shfl_xor(mx, 2));
      mx = fmaxf(mx, __shfl_xor(mx, 4));
      mx = fmaxf(mx, __shfl_xor(mx, 8));
      float m_new = fmaxf(m_s[r], mx);
      float alpha = __expf(m_s[r] - m_new);
      m_s[r] = m_new;
      float p0 = __expf(sf[0][r] - m_new), p1 = __expf(sf[1][r] - m_new);
      float p2 = __expf(sf[2][r] - m_new), p3 = __expf(sf[3][r] - m_new);
      float rs = p0 + p1 + p2 + p3;
      rs += __shfl_xor(rs, 1);
      rs += __shfl_xor(rs, 2);
      rs += __shfl_xor(rs, 4);
      rs += __shfl_xor(rs, 8);
      l_s[r] = l_s[r] * alpha + rs;
#pragma unroll
      for (int nt = 0; nt < 4; nt++) O[nt][r] *= alpha;
      Ps[wave][quad * 4 + r][0 * 16 + lo] = (f16)p0;
      Ps[wave][quad * 4 + r][1 * 16 + lo] = (f16)p1;
      Ps[wave][quad * 4 + r][2 * 16 + lo] = (f16)p2;
      Ps[wave][quad * 4 + r][3 * 16 + lo] = (f16)p3;
    }
    // O += P @ V   (P A-frags from wave-private LDS; wave-order DS ensures visibility)
    half8 ap0 = *(const half8*)&Ps[wave][lo][quad * 8];
    half8 ap1 = *(const half8*)&Ps[wave][lo][32 + quad * 8];
#pragma unroll
    for (int nt = 0; nt < 4; nt++) {
      half8 bv0 = *(const half8*)&Vs[((0 * 4 + quad) * 64 + nt * 16 + lo) * 8];
      half8 bv1 = *(const half8*)&Vs[((1 * 4 + quad) * 64 + nt * 16 + lo) * 8];
      O[nt] = __builtin_amdgcn_mfma_f32_16x16x32_f16(ap0, bv0, O[nt], 0, 0, 0);
      O[nt] = __builtin_amdgcn_mfma_f32_16x16x32_f16(ap1, bv1, O[nt], 0, 0, 0);
    }
    __syncthreads();
  }
  // epilogue: O /= l, store ctx f16 [tok][H]
#pragma unroll
  for (int r = 0; r < 4; r++) {
    float inv = 1.0f / l_s[r];
    long row = (long)b * kSQ + qt * 64 + wave * 16 + quad * 4 + r;
#pragma unroll
    for (int nt = 0; nt < 4; nt++)
      ctx[row * kH + ho + nt * 16 + lo] = (f16)(O[nt][r] * inv);
  }
}

// ---------------- 64x64-tile fp16 MFMA GEMM, BK=64, global_load_lds staging --
// C[M,N] = epilogue(A[M,K] @ B[N,K]^T); B is [N][K] k-contiguous.
struct GemmP {
  const f16* A; long a_row, a_z1, a_z2;
  const f16* Bm; long b_nstr, b_z1, b_z2;
  float* Cf; f16* Ch; long c_row, c_z1, c_z2, c_split; int c_tr;
  const float* bias; long bias_z;
  const float* res; long res_row, res_z1, res_z2;
  float alpha; int gelu; int ksplit;
  int M, N, K, zdiv;
  const int* glist; const int* cnt;  // expert-gather mode: z = expert
};

__global__ __launch_bounds__(256) void gemm_t(GemmP p) {
  __shared__ f16 As[64 * 64];
  __shared__ f16 Bs[64 * 64];
  int z = blockIdx.z;
  int kb = 0, kEnd = p.K, ks = 0;
  if (p.ksplit > 1) {
    int kc = p.K / p.ksplit;
    ks = z % p.ksplit;
    kb = ks * kc;
    kEnd = kb + kc;
    z /= p.ksplit;
  }
  long aoff = 0, boff = 0, coff = 0, roff = 0, biasoff = 0;
  const int* gl = nullptr;
  int Meff = p.M;
  if (p.glist) {
    Meff = p.cnt[z];
    gl = p.glist + (long)z * kTok;
    boff = (long)z * p.b_z2;
    biasoff = (long)z * p.bias_z;
  } else {
    int z1 = z / p.zdiv, z2 = z % p.zdiv;
    aoff = (long)z1 * p.a_z1 + (long)z2 * p.a_z2;
    boff = (long)z1 * p.b_z1 + (long)z2 * p.b_z2;
    coff = (long)z1 * p.c_z1 + (long)z2 * p.c_z2;
    roff = (long)z1 * p.res_z1 + (long)z2 * p.res_z2;
  }
  coff += (long)ks * p.c_split;
  int m0 = blockIdx.y * 64;
  if (m0 >= Meff) return;
  int n0 = blockIdx.x * 64;
  int tid = threadIdx.x, lane = tid & 63, wave = tid >> 6;
  int wm = (wave & 1) * 32, wn = (wave >> 1) * 32;
  int q = lane >> 4, lo = lane & 15;

  const f16* asrc[2];
  const f16* bsrc[2];
#pragma unroll
  for (int s = 0; s < 2; s++) {
    int c = s * 256 + tid;
    int kq = c >> 6, ra = c & 63;
    int row = m0 + ra;
    if (gl) row = gl[row < Meff ? row : Meff - 1];  // clamp: garbage rows never stored
    asrc[s] = p.A + aoff + (long)row * p.a_row + kq * 8;
    bsrc[s] = p.Bm + boff + (long)(n0 + ra) * p.b_nstr + kq * 8;
  }

  f32x4 acc[2][2] = {};
  for (int k0 = kb; k0 < kEnd; k0 += 64) {
#pragma unroll
    for (int s = 0; s < 2; s++) g2l16(asrc[s] + k0, &As[(s * 256 + tid) * 8]);
#pragma unroll
    for (int s = 0; s < 2; s++) g2l16(bsrc[s] + k0, &Bs[(s * 256 + tid) * 8]);
    __syncthreads();
    half8 af[2][2], bf[2][2];
#pragma unroll
    for (int kk = 0; kk < 2; kk++) {
#pragma unroll
      for (int i = 0; i < 2; i++) {
        af[kk][i] = *(const half8*)&As[((kk * 4 + q) * 64 + wm + i * 16 + lo) * 8];
        bf[kk][i] = *(const half8*)&Bs[((kk * 4 + q) * 64 + wn + i * 16 + lo) * 8];
      }
    }
#pragma unroll
    for (int kk = 0; kk < 2; kk++)
#pragma unroll
      for (int i = 0; i < 2; i++)
#pragma unroll
        for (int j = 0; j < 2; j++)
          acc[i][j] = __builtin_amdgcn_mfma_f32_16x16x32_f16(af[kk][i], bf[kk][j], acc[i][j], 0, 0, 0);
    __syncthreads();
  }

#pragma unroll
  for (int i = 0; i < 2; i++) {
#pragma unroll
    for (int j = 0; j < 2; j++) {
      int col = n0 + wn + j * 16 + lo;
      if (p.c_tr) {  // transposed f16 store: 4 consecutive rows -> one 8B store
        int row0 = m0 + wm + i * 16 + q * 4;
        union { f16 h[4]; uint2 u; } o;
#pragma unroll
        for (int r = 0; r < 4; r++) {
          float v = acc[i][j][r];
          if (p.bias) v += p.bias[biasoff + col];
          v *= p.alpha;
          o.h[r] = (f16)v;
        }
        *(uint2*)&p.Ch[coff + (long)col * p.c_row + row0] = o.u;
      } else {
#pragma unroll
        for (int r = 0; r < 4; r++) {
          int row = m0 + wm + i * 16 + q * 4 + r;
          if (row < Meff) {
            long rr = gl ? (long)gl[row] : (long)row;
            float v = acc[i][j][r];
            if (p.bias) v += p.bias[biasoff + col];
            v *= p.alpha;
            if (p.res) v += p.res[roff + rr * p.res_row + col];
            if (p.gelu) v = 0.5f * v * (1.0f + erff(v * 0.70710678118654752f));
            long ci = coff + rr * p.c_row + col;
            if (p.Cf) p.Cf[ci] = v;
            else p.Ch[ci] = (f16)v;
          }
        }
      }
    }
  }
}

extern "C" void kernel_launch(void* const* d_in, const int* in_sizes, int n_in,
                              void* d_out, int out_size, void* d_ws, size_t ws_size,
                              hipStream_t stream) {
  const float* concated = (const float*)d_in[0];
  const float* gen      = (const float*)d_in[1];
  const float* mask     = (const float*)d_in[2];
  const float* ln_g     = (const float*)d_in[3];
  const float* ln_b     = (const float*)d_in[4];
  const float* wq = (const float*)d_in[5];  const float* bq = (const float*)d_in[6];
  const float* wk = (const float*)d_in[7];  const float* bk = (const float*)d_in[8];
  const float* wv = (const float*)d_in[9];  const float* bv = (const float*)d_in[10];
  const float* wo = (const float*)d_in[11]; const float* bo = (const float*)d_in[12];
  const float* gw = (const float*)d_in[13]; const float* gb = (const float*)d_in[14];
  const float* w1 = (const float*)d_in[15]; const float* b1 = (const float*)d_in[16];
  const float* w2 = (const float*)d_in[17]; const float* b2 = (const float*)d_in[18];
  float* out = (float*)d_out;

  size_t off = 0;
  auto alloc = [&](size_t bytes) -> void* {
    void* p = (char*)d_ws + off;
    off += (bytes + 255) & ~(size_t)255;
    return p;
  };
  f16* wq_t  = (f16*)alloc((size_t)kH * kH * 2);       // [N][K]
  f16* wk_t  = (f16*)alloc((size_t)kH * kH * 2);
  f16* wv_t  = (f16*)alloc((size_t)kH * kH * 2);
  f16* wo_t  = (f16*)alloc((size_t)kH * kH * 2);
  f16* w1_t  = (f16*)alloc((size_t)kE * kH * kDFF * 2);  // [E][DFF][H]
  f16* w2_t  = (f16*)alloc((size_t)kE * kDFF * kH * 2);  // [E][H][DFF]
  f16* lnc_h = (f16*)alloc((size_t)kB * kSK * kH * 2);
  f16* lng_h = (f16*)alloc((size_t)kTok * kH * 2);
  f16* q_h   = (f16*)alloc((size_t)kTok * kH * 2);
  f16* k_h   = (f16*)alloc((size_t)kB * kSK * kH * 2);
  f16* v_t   = (f16*)alloc((size_t)kB * kSK * kH * 2);   // [b][h][d][sk]
  f16* ctx_h = (f16*)alloc((size_t)kTok * kH * 2);
  float* ca_f   = (float*)alloc((size_t)kTok * kH * 4);
  float* lnca_f = (float*)alloc((size_t)kTok * kH * 4);
  f16* lnca_h   = (f16*)alloc((size_t)kTok * kH * 2);
  f16* h1_h     = (f16*)alloc((size_t)kTok * kDFF * 2);
  float* part_f = (float*)alloc((size_t)2 * kTok * kH * 4);
  int* cnt_d    = (int*)alloc(kE * 4);
  int* list_d   = (int*)alloc((size_t)kE * kTok * 4);
  int* eid_d    = (int*)alloc((size_t)kTok * 4);

  // ---- weight transpose-convert fp32 [K][N] -> fp16 [N][K] ----
  tr_f2h<<<dim3(32, 32, 1), 256, 0, stream>>>(wq, wq_t, kH, kH);
  tr_f2h<<<dim3(32, 32, 1), 256, 0, stream>>>(wk, wk_t, kH, kH);
  tr_f2h<<<dim3(32, 32, 1), 256, 0, stream>>>(wv, wv_t, kH, kH);
  tr_f2h<<<dim3(32, 32, 1), 256, 0, stream>>>(wo, wo_t, kH, kH);
  tr_f2h<<<dim3(kDFF / 32, kH / 32, kE), 256, 0, stream>>>(w1, w1_t, kH, kDFF);
  tr_f2h<<<dim3(kH / 32, kDFF / 32, kE), 256, 0, stream>>>(w2, w2_t, kDFF, kH);

  // ---- LayerNorms of inputs ----
  ln_kernel<<<kB * kSK, 256, 0, stream>>>(concated, ln_g, ln_b, lnc_h, nullptr, kB * kSK);
  ln_kernel<<<kTok, 256, 0, stream>>>(gen, ln_g, ln_b, lng_h, nullptr, kTok);

  // ---- Q projection (scale 0.125 folded) ----
  {
    GemmP p{}; p.A = lng_h; p.a_row = kH;
    p.Bm = wq_t; p.b_nstr = kH;
    p.Ch = q_h; p.c_row = kH; p.bias = bq; p.alpha = 0.125f;
    p.M = kTok; p.N = kH; p.K = kH; p.zdiv = 1;
    gemm_t<<<dim3(kH / 64, kTok / 64, 1), 256, 0, stream>>>(p);
  }
  // ---- K projection ----
  {
    GemmP p{}; p.A = lnc_h; p.a_row = kH;
    p.Bm = wk_t; p.b_nstr = kH;
    p.Ch = k_h; p.c_row = kH; p.bias = bk; p.alpha = 1.0f;
    p.M = kB * kSK; p.N = kH; p.K = kH; p.zdiv = 1;
    gemm_t<<<dim3(kH / 64, kB * kSK / 64, 1), 256, 0, stream>>>(p);
  }
  // ---- V projection, transposed store into v_t[b][h][d][sk]; z = batch ----
  {
    GemmP p{}; p.A = lnc_h; p.a_row = kH; p.a_z1 = (long)kSK * kH; p.a_z2 = 0;
    p.Bm = wv_t; p.b_nstr = kH; p.b_z1 = 0; p.b_z2 = 0;
    p.Ch = v_t; p.c_row = kSK; p.c_z1 = (long)kH * kSK; p.c_z2 = 0; p.c_tr = 1;
    p.bias = bv; p.alpha = 1.0f;
    p.M = kSK; p.N = kH; p.K = kH; p.zdiv = 1;
    gemm_t<<<dim3(kH / 64, kSK / 64, kB), 256, 0, stream>>>(p);
  }
  // ---- fused flash attention -> ctx_h ----
  flash_kernel<<<dim3(kSQ / 64, kB * kHeads), 256, 0, stream>>>(q_h, k_h, v_t, mask, ctx_h);
  // ---- ca_out = ctx @ wo^T + bo + gen (fp32 out) ----
  {
    GemmP p{}; p.A = ctx_h; p.a_row = kH;
    p.Bm = wo_t; p.b_nstr = kH;
    p.Cf = ca_f; p.c_row = kH; p.bias = bo;
    p.res = gen; p.res_row = kH;
    p.alpha = 1.0f; p.M = kTok; p.N = kH; p.K = kH; p.zdiv = 1;
    gemm_t<<<dim3(kH / 64, kTok / 64, 1), 256, 0, stream>>>(p);
  }
  // ---- ln_ca (fp32 + fp16) ----
  ln_kernel<<<kTok, 256, 0, stream>>>(ca_f, ln_g, ln_b, lnca_h, lnca_f, kTok);
  // ---- router + expert bucketing ----
  zero_kernel<<<1, 64, 0, stream>>>(cnt_d, kE);
  router_kernel<<<kTok, 64, 0, stream>>>(ca_f, gw, gb, cnt_d, list_d, eid_d);
  // ---- FFN1: h1 = gelu(ln_ca @ w1[e] + b1[e]) ----
  {
    GemmP p{}; p.A = lnca_h; p.a_row = kH;
    p.Bm = w1_t; p.b_nstr = kH; p.b_z2 = (long)kH * kDFF;
    p.Ch = h1_h; p.c_row = kDFF; p.bias = b1; p.bias_z = kDFF;
    p.alpha = 1.0f; p.gelu = 1; p.M = kTok; p.N = kDFF; p.K = kH; p.zdiv = 1;
    p.glist = list_d; p.cnt = cnt_d;
    gemm_t<<<dim3(kDFF / 64, kTok / 64, kE), 256, 0, stream>>>(p);
  }
  // ---- FFN2: part[s] = h1 @ w2[e] (split-K x2, fp32 partials, no atomics) ----
  {
    GemmP p{}; p.A = h1_h; p.a_row = kDFF;
    p.Bm = w2_t; p.b_nstr = kDFF; p.b_z2 = (long)kDFF * kH;
    p.Cf = part_f; p.c_row = kH; p.c_split = (long)kTok * kH;
    p.alpha = 1.0f; p.ksplit = 2;
    p.M = kTok; p.N = kH; p.K = kDFF; p.zdiv = 1;
    p.glist = list_d; p.cnt = cnt_d;
    gemm_t<<<dim3(kH / 64, kTok / 64, kE * 2), 256, 0, stream>>>(p);
  }
  // ---- reduce: out = part0 + part1 + b2[eid] + lnca ----
  ffn2_reduce<<<kTok, 256, 0, stream>>>(part_f, lnca_f, b2, eid_d, out);
}